// Round 7
// baseline (791.954 us; speedup 1.0000x reference)
//
#include <hip/hip_runtime.h>

// ============================================================================
// MoE block (top-2 of 8 experts), T=8192 tokens, d=1024, h=2048.
// R7: overhead elimination. phase1 stages A straight from fp32 x (load+cvt+
// ds_write, no Xg / no gather kernel); phase2 stages B straight from fp32 w2
// (no w2b conversion); head converts only w1; finalize+fill merged into one
// single-block kernel. 5 kernels total: head -> finfill -> phase1 -> phase2
// -> combine. GEMM cores keep: 128x128 tile, BK=32 single-buffer, XCD
// swizzle, global_load_lds(16B) for the bf16 operand.
//
// ws layout (bytes):
//   0       counts[8] / 64 offsets[9] / 128 cursors[8] / 192 tileoff[9]
//   256     topk_idx[16384] int
//   65792   topk_gate[16384] float
//   131328  block_probsum[2048*8] float
//   196864  assign_token[16384] int
//   262400  (free)
//   327936  posinv[16384] int            (token*2+k -> packed row)
//   1 MB    (free, was Xg)
//   +34.8MB w1b[8*2048*1024] bf16        (33.6 MB)
//   +       (free, was w2b)
//   +       Hbuf[(16384+128) x 2048] bf16 (67.6 MB)
//   +       Y[(16384+128) x 1024] bf16    (33.8 MB)
// ============================================================================

#define TOKS 8192
#define DIMD 1024
#define HID  2048
#define NE   8

#define OFF_COUNTS   0
#define OFF_OFFSETS  64
#define OFF_CURSORS  128
#define OFF_TILEOFF  192
#define OFF_TOPKI    256
#define OFF_TOPKG    (OFF_TOPKI + TOKS*2*4)
#define OFF_BLKPS    (OFF_TOPKG + TOKS*2*4)
#define OFF_ATOK     (OFF_BLKPS + 2048*NE*4)
#define OFF_PINV     (OFF_ATOK + TOKS*2*4 + TOKS*2*4)
#define OFF_XG       (1u << 20)
#define XG_ROWS      (TOKS*2 + 128)
#define OFF_W1B      (OFF_XG  + (size_t)XG_ROWS * DIMD * 2)
#define OFF_W2B      (OFF_W1B + (size_t)NE * HID * DIMD * 2)
#define OFF_H        (OFF_W2B + (size_t)NE * DIMD * HID * 2)
#define OFF_Y        (OFF_H   + (size_t)XG_ROWS * HID * 2)

typedef __bf16 bf16x8 __attribute__((ext_vector_type(8)));
typedef float  floatx4 __attribute__((ext_vector_type(4)));
typedef unsigned short ushortx8 __attribute__((ext_vector_type(8)));

__device__ __forceinline__ float bf2f(unsigned short u) {
    return __uint_as_float(((unsigned)u) << 16);
}
__device__ __forceinline__ unsigned short f2bf(float f) {
    unsigned u = __float_as_uint(f);
    unsigned r = (u + 0x7FFFu + ((u >> 16) & 1u)) >> 16;
    return (unsigned short)r;
}
__device__ __forceinline__ ushortx8 cvt8(float4 a, float4 b) {
    ushortx8 r;
    r[0] = f2bf(a.x); r[1] = f2bf(a.y); r[2] = f2bf(a.z); r[3] = f2bf(a.w);
    r[4] = f2bf(b.x); r[5] = f2bf(b.y); r[6] = f2bf(b.z); r[7] = f2bf(b.w);
    return r;
}

#define GLOBAL_AS(p) ((const __attribute__((address_space(1))) unsigned int*)(p))
#define LDS_AS(p)    ((__attribute__((address_space(3))) unsigned int*)(p))

// ---------------------------------------------------------------------------
// head: blocks [0,2048) router (1 wave/token); blocks [2048,6144) convert w1.
__global__ __launch_bounds__(256) void head_kernel(
    const float* __restrict__ x, const float* __restrict__ rw,
    int* __restrict__ topki, float* __restrict__ topkg,
    float* __restrict__ blkps,
    const float4* __restrict__ w1, ushort4* __restrict__ w1b, int n1)
{
    if (blockIdx.x >= 2048) {
        int i = (blockIdx.x - 2048) * 256 + threadIdx.x;
        int stride = 4096 * 256;
        for (; i < n1; i += stride) {
            float4 v = w1[i];
            ushort4 o;
            o.x = f2bf(v.x); o.y = f2bf(v.y); o.z = f2bf(v.z); o.w = f2bf(v.w);
            w1b[i] = o;
        }
        return;
    }

    int wave = threadIdx.x >> 6;
    int lane = threadIdx.x & 63;
    int t = blockIdx.x * 4 + wave;
    const float* xt = x + (size_t)t * DIMD;

    float acc[NE];
#pragma unroll
    for (int e = 0; e < NE; e++) acc[e] = 0.f;
    for (int i = 0; i < DIMD / 64; i++) {
        float xv = xt[lane + 64 * i];
#pragma unroll
        for (int e = 0; e < NE; e++) acc[e] += xv * rw[e * DIMD + lane + 64 * i];
    }
#pragma unroll
    for (int off = 32; off > 0; off >>= 1) {
#pragma unroll
        for (int e = 0; e < NE; e++) acc[e] += __shfl_down(acc[e], off);
    }

    __shared__ float ps[4][NE];
    if (lane == 0) {
        float m = acc[0];
#pragma unroll
        for (int e = 1; e < NE; e++) m = fmaxf(m, acc[e]);
        float ex[NE], s = 0.f;
#pragma unroll
        for (int e = 0; e < NE; e++) { ex[e] = expf(acc[e] - m); s += ex[e]; }
        float inv = 1.f / s;
#pragma unroll
        for (int e = 0; e < NE; e++) ps[wave][e] = ex[e] * inv;

        int i0 = 0; float l0 = acc[0];
#pragma unroll
        for (int e = 1; e < NE; e++) if (acc[e] > l0) { l0 = acc[e]; i0 = e; }
        int i1 = -1; float l1 = -3.4e38f;
#pragma unroll
        for (int e = 0; e < NE; e++) if (e != i0 && acc[e] > l1) { l1 = acc[e]; i1 = e; }
        float e1 = expf(l1 - l0);
        float g0 = 1.f / (1.f + e1);
        float g1 = e1 * g0;
        topki[t * 2 + 0] = i0; topki[t * 2 + 1] = i1;
        topkg[t * 2 + 0] = g0; topkg[t * 2 + 1] = g1;
    }
    __syncthreads();
    if (threadIdx.x < NE) {
        float s = ps[0][threadIdx.x] + ps[1][threadIdx.x] + ps[2][threadIdx.x] + ps[3][threadIdx.x];
        blkps[blockIdx.x * NE + threadIdx.x] = s;
    }
}

// ---------------------------------------------------------------------------
// finfill: ONE block. counts -> offsets/tileoff/aux -> packed fill with LDS
// cursors + wave-ballot aggregation. Order within an expert list is free.
__global__ __launch_bounds__(256) void finfill_kernel(
    const int* __restrict__ topki, const float* __restrict__ topkg,
    const float* __restrict__ blkps,
    int* __restrict__ counts, int* __restrict__ offsets,
    int* __restrict__ tileoff, float* __restrict__ aux_out,
    int* __restrict__ atok, int* __restrict__ posinv)
{
    __shared__ float psum[NE];
    __shared__ int cnt[NE];
    __shared__ int curs[NE];
    int tid = threadIdx.x;
    if (tid < NE) { psum[tid] = 0.f; cnt[tid] = 0; }
    __syncthreads();

    float lp[NE]; int lc[NE];
#pragma unroll
    for (int e = 0; e < NE; e++) { lp[e] = 0.f; lc[e] = 0; }
    const float4* bp4 = (const float4*)blkps;
    for (int i = tid; i < 2048 * NE / 4; i += 256) {
        float4 v = bp4[i];
        int eb = (4 * i) & 7;
        lp[eb + 0] += v.x; lp[eb + 1] += v.y; lp[eb + 2] += v.z; lp[eb + 3] += v.w;
    }
    const int4* ti4 = (const int4*)topki;
    for (int i = tid; i < TOKS * 2 / 4; i += 256) {
        int4 v = ti4[i];
        lc[v.x]++; lc[v.y]++; lc[v.z]++; lc[v.w]++;
    }
#pragma unroll
    for (int e = 0; e < NE; e++) { atomicAdd(&psum[e], lp[e]); atomicAdd(&cnt[e], lc[e]); }
    __syncthreads();

    if (tid == 0) {
        int off = 0, to = 0;
        for (int e = 0; e < NE; e++) {
            counts[e] = cnt[e];
            offsets[e] = off;
            curs[e] = off;
            tileoff[e] = to;
            off += cnt[e];
            to += (cnt[e] + 127) >> 7;
        }
        offsets[NE] = off; tileoff[NE] = to;
        float aux = 0.f;
        for (int e = 0; e < NE; e++)
            aux += ((float)cnt[e] / (float)(TOKS * 2)) * (psum[e] / (float)TOKS);
        aux_out[0] = (float)NE * aux;
    }
    __syncthreads();

    int lane = tid & 63;
    unsigned long long below = (1ull << lane) - 1ull;
    for (int i = tid; i < TOKS * 2; i += 256) {
        int e = topki[i];
        for (int ee = 0; ee < NE; ee++) {
            bool pred = (e == ee);
            unsigned long long mask = __ballot(pred ? 1 : 0);
            if (mask) {
                int leader = __ffsll((unsigned long long)mask) - 1;
                int base = 0;
                if (lane == leader) base = atomicAdd(&curs[ee], (int)__popcll(mask));
                base = __shfl(base, leader);
                if (pred) {
                    int pos = base + (int)__popcll(mask & below);
                    atok[pos] = i >> 1;
                    posinv[i] = pos;
                }
            }
        }
    }
}

// ---------------------------------------------------------------------------
// phase1: H[r,:] = gelu(x[atok(r),:] @ w1b[e]^T + b1[e]), bf16 out.
// A staged from fp32 x (load+cvt+ds_write); B via global_load_lds from w1b.
__global__ __launch_bounds__(256) void phase1_kernel(
    const float* __restrict__ x, const ushort* __restrict__ w1b,
    const float* __restrict__ b1,
    const int* __restrict__ counts, const int* __restrict__ offsets,
    const int* __restrict__ tileoff, const int* __restrict__ atok,
    unsigned short* __restrict__ Hbuf)
{
    const int NCOLT = HID / 128;   // 16
    int total = tileoff[NE] * NCOLT;
    int chunk = gridDim.x >> 3;
    int idx = (blockIdx.x & 7) * chunk + (blockIdx.x >> 3);
    if (idx >= total) return;
    int ct = idx & (NCOLT - 1);
    int rowt = idx / NCOLT;
    int e = 0;
    while (rowt >= tileoff[e + 1]) e++;
    int row0 = (rowt - tileoff[e]) * 128;
    int cnt = counts[e];
    int base = offsets[e];
    int colbase = ct * 128;

    __shared__ ushort ldsA[128 * 32];
    __shared__ ushort ldsB[128 * 32];

    int tid = threadIdx.x;
    int lane = tid & 63;
    int wave = tid >> 6;
    int wrow = wave >> 1, wcol = wave & 1;
    int l15 = lane & 15, quad = lane >> 4;

    // A source rows (fp32 x, gathered via atok; clamp OOB rows to token 0)
    int r0 = row0 + 16 * (2 * wave)     + l15;
    int r1 = row0 + 16 * (2 * wave + 1) + l15;
    int tok0 = (r0 < cnt) ? atok[base + r0] : 0;
    int tok1 = (r1 < cnt) ? atok[base + r1] : 0;
    const float* xr0 = x + (size_t)tok0 * DIMD + quad * 8;
    const float* xr1 = x + (size_t)tok1 * DIMD + quad * 8;
    ushortx8* wA0 = (ushortx8*)&ldsA[(2 * wave) * 512 + lane * 8];
    ushortx8* wA1 = (ushortx8*)&ldsA[(2 * wave + 1) * 512 + lane * 8];

    // B via DMA (bf16 w1b)
    const ushort* wB  = w1b + (size_t)e * HID * DIMD;
    const ushort* gB0 = wB + (size_t)(colbase + 16 * (2 * wave)     + l15) * DIMD + quad * 8;
    const ushort* gB1 = wB + (size_t)(colbase + 16 * (2 * wave + 1) + l15) * DIMD + quad * 8;
    ushort* ldB0 = &ldsB[(2 * wave) * 512];
    ushort* ldB1 = &ldsB[(2 * wave + 1) * 512];

    floatx4 acc[4][4];
#pragma unroll
    for (int i = 0; i < 4; i++)
#pragma unroll
        for (int j = 0; j < 4; j++) acc[i][j] = (floatx4){0.f, 0.f, 0.f, 0.f};

    const bf16x8* fA = reinterpret_cast<const bf16x8*>(ldsA);
    const bf16x8* fB = reinterpret_cast<const bf16x8*>(ldsB);

    for (int k0 = 0; k0 < DIMD; k0 += 32) {
        float4 a00 = *(const float4*)(xr0 + k0);
        float4 a01 = *(const float4*)(xr0 + k0 + 4);
        float4 a10 = *(const float4*)(xr1 + k0);
        float4 a11 = *(const float4*)(xr1 + k0 + 4);
        __syncthreads();
        __builtin_amdgcn_global_load_lds(GLOBAL_AS(gB0), LDS_AS(ldB0), 16, 0, 0);
        __builtin_amdgcn_global_load_lds(GLOBAL_AS(gB1), LDS_AS(ldB1), 16, 0, 0);
        gB0 += 32; gB1 += 32;
        *wA0 = cvt8(a00, a01);
        *wA1 = cvt8(a10, a11);
        __syncthreads();

        bf16x8 a[4], b[4];
#pragma unroll
        for (int i = 0; i < 4; i++) a[i] = fA[(4 * wrow + i) * 64 + lane];
#pragma unroll
        for (int j = 0; j < 4; j++) b[j] = fB[(4 * wcol + j) * 64 + lane];
#pragma unroll
        for (int i = 0; i < 4; i++)
#pragma unroll
            for (int j = 0; j < 4; j++)
                acc[i][j] = __builtin_amdgcn_mfma_f32_16x16x32_bf16(a[i], b[j], acc[i][j], 0, 0, 0);
    }

    // epilogue: bias + exact GELU, bf16 store. C/D: col=lane&15, row=quad*4+reg
#pragma unroll
    for (int i = 0; i < 4; i++) {
#pragma unroll
        for (int r = 0; r < 4; r++) {
            int pr = row0 + 64 * wrow + 16 * i + quad * 4 + r;
            if (pr < cnt) {
                size_t hrow = (size_t)(base + pr) * HID;
#pragma unroll
                for (int j = 0; j < 4; j++) {
                    int col = colbase + 64 * wcol + 16 * j + l15;
                    float v = acc[i][j][r] + b1[e * HID + col];
                    v = 0.5f * v * (1.f + erff(v * 0.70710678118654752f));
                    Hbuf[hrow + col] = f2bf(v);
                }
            }
        }
    }
}

// ---------------------------------------------------------------------------
// phase2: Y[r,:] = H[r,:] @ w2[e]^T (raw, bf16 out). A via DMA from Hbuf;
// B staged from fp32 w2 (load+cvt+ds_write).
__global__ __launch_bounds__(256) void phase2_kernel(
    const ushort* __restrict__ Hbuf, const float* __restrict__ w2,
    const int* __restrict__ counts, const int* __restrict__ offsets,
    const int* __restrict__ tileoff, ushort* __restrict__ Y)
{
    const int NCOLT = DIMD / 128;  // 8
    int total = tileoff[NE] * NCOLT;
    int chunk = gridDim.x >> 3;
    int idx = (blockIdx.x & 7) * chunk + (blockIdx.x >> 3);
    if (idx >= total) return;
    int ct = idx & (NCOLT - 1);
    int rowt = idx / NCOLT;
    int e = 0;
    while (rowt >= tileoff[e + 1]) e++;
    int row0 = (rowt - tileoff[e]) * 128;
    int cnt = counts[e];
    int base = offsets[e];
    int colbase = ct * 128;

    __shared__ ushort ldsA[128 * 32];
    __shared__ ushort ldsB[128 * 32];

    int tid = threadIdx.x;
    int lane = tid & 63;
    int wave = tid >> 6;
    int wrow = wave >> 1, wcol = wave & 1;
    int l15 = lane & 15, quad = lane >> 4;

    const ushort* gA0 = Hbuf + (size_t)(base + row0 + 16 * (2 * wave)     + l15) * HID + quad * 8;
    const ushort* gA1 = Hbuf + (size_t)(base + row0 + 16 * (2 * wave + 1) + l15) * HID + quad * 8;
    ushort* ldA0 = &ldsA[(2 * wave) * 512];
    ushort* ldA1 = &ldsA[(2 * wave + 1) * 512];

    // B source rows (fp32 w2)
    const float* wB = w2 + (size_t)e * DIMD * HID;
    const float* wr0 = wB + (size_t)(colbase + 16 * (2 * wave)     + l15) * HID + quad * 8;
    const float* wr1 = wB + (size_t)(colbase + 16 * (2 * wave + 1) + l15) * HID + quad * 8;
    ushortx8* wBw0 = (ushortx8*)&ldsB[(2 * wave) * 512 + lane * 8];
    ushortx8* wBw1 = (ushortx8*)&ldsB[(2 * wave + 1) * 512 + lane * 8];

    floatx4 acc[4][4];
#pragma unroll
    for (int i = 0; i < 4; i++)
#pragma unroll
        for (int j = 0; j < 4; j++) acc[i][j] = (floatx4){0.f, 0.f, 0.f, 0.f};

    const bf16x8* fA = reinterpret_cast<const bf16x8*>(ldsA);
    const bf16x8* fB = reinterpret_cast<const bf16x8*>(ldsB);

    for (int k0 = 0; k0 < HID; k0 += 32) {
        float4 b00 = *(const float4*)(wr0 + k0);
        float4 b01 = *(const float4*)(wr0 + k0 + 4);
        float4 b10 = *(const float4*)(wr1 + k0);
        float4 b11 = *(const float4*)(wr1 + k0 + 4);
        __syncthreads();
        __builtin_amdgcn_global_load_lds(GLOBAL_AS(gA0), LDS_AS(ldA0), 16, 0, 0);
        __builtin_amdgcn_global_load_lds(GLOBAL_AS(gA1), LDS_AS(ldA1), 16, 0, 0);
        gA0 += 32; gA1 += 32;
        *wBw0 = cvt8(b00, b01);
        *wBw1 = cvt8(b10, b11);
        __syncthreads();

        bf16x8 a[4], b[4];
#pragma unroll
        for (int i = 0; i < 4; i++) a[i] = fA[(4 * wrow + i) * 64 + lane];
#pragma unroll
        for (int j = 0; j < 4; j++) b[j] = fB[(4 * wcol + j) * 64 + lane];
#pragma unroll
        for (int i = 0; i < 4; i++)
#pragma unroll
            for (int j = 0; j < 4; j++)
                acc[i][j] = __builtin_amdgcn_mfma_f32_16x16x32_bf16(a[i], b[j], acc[i][j], 0, 0, 0);
    }

    // epilogue: plain bf16 store (bias+gate applied in combine)
#pragma unroll
    for (int i = 0; i < 4; i++) {
#pragma unroll
        for (int r = 0; r < 4; r++) {
            int pr = row0 + 64 * wrow + 16 * i + quad * 4 + r;
            if (pr < cnt) {
                size_t yrow = (size_t)(base + pr) * DIMD;
#pragma unroll
                for (int j = 0; j < 4; j++) {
                    int col = colbase + 64 * wcol + 16 * j + l15;
                    Y[yrow + col] = f2bf(acc[i][j][r]);
                }
            }
        }
    }
}

// ---------------------------------------------------------------------------
// Combine: out[t,:] = g0*(Y[p0,:]+b2[e0,:]) + g1*(Y[p1,:]+b2[e1,:]).
__global__ __launch_bounds__(256) void combine_kernel(
    const ushort* __restrict__ Y, const float* __restrict__ b2,
    const int* __restrict__ topki, const float* __restrict__ topkg,
    const int* __restrict__ posinv, float* __restrict__ out)
{
    int wave = threadIdx.x >> 6;
    int lane = threadIdx.x & 63;
    int t = blockIdx.x * 4 + wave;
    int e0 = topki[t * 2 + 0], e1 = topki[t * 2 + 1];
    float g0 = topkg[t * 2 + 0], g1 = topkg[t * 2 + 1];
    int p0 = posinv[t * 2 + 0], p1 = posinv[t * 2 + 1];

    const ushort4* y0 = (const ushort4*)(Y + (size_t)p0 * DIMD);
    const ushort4* y1 = (const ushort4*)(Y + (size_t)p1 * DIMD);
    const float4* b20 = (const float4*)(b2 + (size_t)e0 * DIMD);
    const float4* b21 = (const float4*)(b2 + (size_t)e1 * DIMD);
    float4* o4 = (float4*)(out + (size_t)t * DIMD);

#pragma unroll
    for (int c = 0; c < DIMD / 4 / 64; c++) {   // 4 iterations
        int i = lane + 64 * c;
        ushort4 a = y0[i], b = y1[i];
        float4 ba = b20[i], bb = b21[i];
        float4 r;
        r.x = g0 * (bf2f(a.x) + ba.x) + g1 * (bf2f(b.x) + bb.x);
        r.y = g0 * (bf2f(a.y) + ba.y) + g1 * (bf2f(b.y) + bb.y);
        r.z = g0 * (bf2f(a.z) + ba.z) + g1 * (bf2f(b.z) + bb.z);
        r.w = g0 * (bf2f(a.w) + ba.w) + g1 * (bf2f(b.w) + bb.w);
        o4[i] = r;
    }
}

// ---------------------------------------------------------------------------
extern "C" void kernel_launch(void* const* d_in, const int* in_sizes, int n_in,
                              void* d_out, int out_size, void* d_ws, size_t ws_size,
                              hipStream_t stream) {
    const float* x  = (const float*)d_in[0];
    const float* rw = (const float*)d_in[1];
    const float* w1 = (const float*)d_in[2];
    const float* b1 = (const float*)d_in[3];
    const float* w2 = (const float*)d_in[4];
    const float* b2 = (const float*)d_in[5];
    float* out = (float*)d_out;

    char* ws = (char*)d_ws;
    int*   counts  = (int*)(ws + OFF_COUNTS);
    int*   offsets = (int*)(ws + OFF_OFFSETS);
    int*   tileoff = (int*)(ws + OFF_TILEOFF);
    int*   topki   = (int*)(ws + OFF_TOPKI);
    float* topkg   = (float*)(ws + OFF_TOPKG);
    float* blkps   = (float*)(ws + OFF_BLKPS);
    int*   atok    = (int*)(ws + OFF_ATOK);
    int*   posinv  = (int*)(ws + OFF_PINV);
    ushort* w1b    = (ushort*)(ws + OFF_W1B);
    ushort* Hbuf   = (ushort*)(ws + OFF_H);
    ushort* Y      = (ushort*)(ws + OFF_Y);

    // router (blocks 0..2047) + w1 conversion (blocks 2048..6143)
    head_kernel<<<6144, 256, 0, stream>>>(
        x, rw, topki, topkg, blkps,
        (const float4*)w1, (ushort4*)w1b, NE * HID * DIMD / 4);

    finfill_kernel<<<1, 256, 0, stream>>>(topki, topkg, blkps, counts, offsets,
                                          tileoff, out + (size_t)TOKS * DIMD,
                                          atok, posinv);

    // worst-case 128-row tiles: sum_e ceil(cnt_e/128) <= 16384/128 + 7 = 135
    // grids divisible by 8 for the XCD swizzle: 135*16=2160, 135*8=1080
    phase1_kernel<<<135 * (HID / 128), 256, 0, stream>>>(
        x, w1b, b1, counts, offsets, tileoff, atok, Hbuf);
    phase2_kernel<<<135 * (DIMD / 128), 256, 0, stream>>>(
        Hbuf, w2, counts, offsets, tileoff, Y);
    combine_kernel<<<TOKS / 4, 256, 0, stream>>>(Y, b2, topki, topkg, posinv, out);
}